// Round 11
// baseline (135.703 us; speedup 1.0000x reference)
//
#include <hip/hip_runtime.h>

// Problem constants (fixed by setup_inputs)
#define N_PED 2048
#define NGROUP 64
#define NPG 32        // peds per group
#define HDIM 128
#define DIN 64
#define DDIM 64
#define NHEAD 4
#define TOBS 8

typedef __attribute__((ext_vector_type(8))) short bf16x8;
typedef __attribute__((ext_vector_type(4))) float f32x4;

__device__ __forceinline__ float sigm(float x){
    return __builtin_amdgcn_rcpf(1.f + __expf(-x));
}
__device__ __forceinline__ float tanh_fast(float x){
    return 1.f - 2.f*__builtin_amdgcn_rcpf(__expf(2.f*x) + 1.f);
}
__device__ __forceinline__ short f2bf(float f){
    unsigned u = __float_as_uint(f);
    unsigned r = (u + 0x7fffu + ((u >> 16) & 1u)) >> 16;   // RNE
    return (short)r;
}
__device__ __forceinline__ float bf2f(unsigned short b){
    return __uint_as_float(((unsigned)b) << 16);
}
__device__ __forceinline__ unsigned pk2(float a, float b){
    return (unsigned)(unsigned short)f2bf(a) | ((unsigned)(unsigned short)f2bf(b) << 16);
}

// ws layout (bytes):
//   AHb  @ 0        : 2048*128 ushort (bf16)      524288
//   TAHb @ 524288   : 2048*128 ushort             524288
//   VW   @ 1048576  : 1024 f32 (V | W1)             4096
//   Gf   @ 1052672  : W_gate B-frags  16*64*16B    16384
//   Wf   @ 1069056  : gat_w  B-frags 128*64*16B   131072
//   Lf   @ 1200128  : LSTM W B-frags 192*64*16B   196608
//   BSV  @ 1396736  : b_ih+b_hh fused, 512 f32      2048
//   GATE @ 1398784  : gate[i][j][f] bf16, 2048*32*128  16777216
#define WS_AHB   0
#define WS_TAHB  524288
#define WS_VW    1048576
#define WS_GF    1052672
#define WS_WF    1069056
#define WS_LF    1200128
#define WS_BSV   1396736
#define WS_GATE  1398784

// ---------------------------------------------------------------------------
// D1: pack what D2 needs. Blocks 0..23: Lf (LSTM weight B-frags);
// 24: fused bias; 25..26: Gf (W_gate B-frags, consumed by D2's gate-MLP).
// ---------------------------------------------------------------------------
__global__ __launch_bounds__(512) void pack1_kernel(
    const float* __restrict__ W_ih,  const float* __restrict__ W_hh,
    const float* __restrict__ b_ih,  const float* __restrict__ b_hh,
    const float* __restrict__ W_gate,
    unsigned char* __restrict__ ws)
{
    const int tid = threadIdx.x;
    const int b   = blockIdx.x;
    if (b < 24) {
        // Lf pack: fid = (w*4+idx)*6+kt ; lane L = (q,ln) holds
        //   Wcat[k = kt*32+q*8+j][n = idx*128 + w*16 + ln], j=0..7
        const int id = b*512 + tid;             // 0..12287
        const int fid = id >> 6, L = id & 63;
        const int kt  = fid % 6;
        const int wi  = fid / 6;                // w*4 + idx
        const int w   = wi >> 2, idx = wi & 3;
        const int q = L >> 4, ln = L & 15;
        const int n = idx*128 + w*16 + ln;
        float v[8];
        if (kt < 2) {
            const float* src = W_ih + (size_t)n*DIN + kt*32 + q*8;
            #pragma unroll
            for (int j = 0; j < 8; ++j) v[j] = src[j];
        } else {
            const float* src = W_hh + (size_t)n*HDIM + (kt-2)*32 + q*8;
            #pragma unroll
            for (int j = 0; j < 8; ++j) v[j] = src[j];
        }
        reinterpret_cast<uint4*>(ws + WS_LF)[id] =
            uint4{ pk2(v[0],v[1]), pk2(v[2],v[3]), pk2(v[4],v[5]), pk2(v[6],v[7]) };
    } else if (b == 24) {
        ((float*)(ws + WS_BSV))[tid] = b_ih[tid] + b_hh[tid];
    } else {
        // Gf pack: 1024 records
        const int id = (b - 25)*512 + tid;      // 0..1023
        const int fid = id >> 6, L = id & 63;
        const int kt = fid >> 3, nt = fid & 7;
        const int q = L >> 4, ln = L & 15;
        float v[8];
        #pragma unroll
        for (int j = 0; j < 8; ++j)
            v[j] = W_gate[(size_t)(kt*32 + q*8 + j)*HDIM + nt*16 + ln];
        reinterpret_cast<uint4*>(ws + WS_GF)[id] =
            uint4{ pk2(v[0],v[1]), pk2(v[2],v[3]), pk2(v[4],v[5]), pk2(v[6],v[7]) };
    }
}

// ---------------------------------------------------------------------------
// D2: 544 blocks.
//   0..255   : LSTM (R9/R10 structure — measured best)
//   256..271 : prep VW (V/W1 projections, gat-only)
//   272..287 : Wf pack (gat_w B-frags, gat-only)
//   288..543 : gate-MLP — gate[i][j][f] for ALL pairs (independent of LSTM;
//              backfills CUs as lstm blocks drain). This removes phases
//              (a)+(b) (its MFMA + sigmoids + 2 barriers) from gat's
//              critical path.
// ---------------------------------------------------------------------------
#define KPAD 216
__global__ __launch_bounds__(512) void lstm_fused_kernel(
    const float* __restrict__ obs, const float* __restrict__ h0,
    const float* __restrict__ c0,  const float* __restrict__ W_emb,
    const float* __restrict__ b_emb,
    const float* __restrict__ gat_w, const float* __restrict__ gat_a,
    const float* __restrict__ action, const float* __restrict__ goal,
    const float* __restrict__ W_dist, const float* __restrict__ b_dist,
    const float* __restrict__ b_gate,
    unsigned char* __restrict__ ws,
    unsigned short* __restrict__ AHb, unsigned short* __restrict__ TAHb)
{
    const int tid = threadIdx.x;

    if (blockIdx.x >= 256) {
        const int vb = blockIdx.x - 256;
        if (vb < 16) {
            // ---- prep: V[h][f] = w[h][f]·a2, W1[h][f] = w[h][f]·a1 ----
            __shared__ float sa[2*HDIM];
            __shared__ float red[32][8][2];
            float* VW = (float*)(ws + WS_VW);
            if (tid < 256) sa[tid] = gat_a[tid];
            __syncthreads();
            const int rl = (tid & 255) >> 3, ch = tid & 7;
            const int row = vb*32 + rl;          // row = h*128 + f
            if (tid < 256) {
                const float* rp = gat_w + (size_t)row*HDIM + ch*16;
                float v = 0.f, w1 = 0.f;
                #pragma unroll
                for (int e = 0; e < 16; ++e) {
                    float wv = rp[e];
                    v  += wv * sa[HDIM + ch*16 + e];
                    w1 += wv * sa[ch*16 + e];
                }
                red[rl][ch][0] = v; red[rl][ch][1] = w1;
            }
            __syncthreads();
            if (tid < 256 && ch == 0) {
                float sv = 0.f, sw = 0.f;
                #pragma unroll
                for (int e = 0; e < 8; ++e) { sv += red[rl][e][0]; sw += red[rl][e][1]; }
                VW[row]       = sv;
                VW[512 + row] = sw;
            }
        } else if (vb < 32) {
            // ---- Wf pack: 8192 records ----
            const int id = (vb - 16)*512 + tid;  // 0..8191
            const int fid = id >> 6, L = id & 63;
            const int kt = fid >> 3, nt = fid & 7;
            const int q = L >> 4, ln = L & 15;
            float v[8];
            #pragma unroll
            for (int j = 0; j < 8; ++j) {
                int F = kt*32 + q*8 + j;               // F = h*128 + f
                v[j] = gat_w[(size_t)(F >> 7)*16384 + (size_t)(F & 127)*HDIM + nt*16 + ln];
            }
            reinterpret_cast<uint4*>(ws + WS_WF)[id] =
                uint4{ pk2(v[0],v[1]), pk2(v[2],v[3]), pk2(v[4],v[5]), pk2(v[6],v[7]) };
        } else {
            // ---- gate-MLP: 256 blocks, block = (group g, 8 i-rows) ----
            const int vb2 = blockIdx.x - 288;    // 0..255
            const int g   = vb2 >> 2;
            const int i0  = (vb2 & 3) * 8;
            const int p0  = g * NPG;
            __shared__ float gBase[8][64];
            __shared__ float gDyn[32][64];
            {
                int il = tid >> 6, k = tid & 63; // 512 = 8 x 64
                float2 ac = reinterpret_cast<const float2*>(action)[p0 + i0 + il];
                float2 gl = reinterpret_cast<const float2*>(goal)[p0 + i0 + il];
                gBase[il][k] = ac.x*W_dist[k] + ac.y*W_dist[64+k]
                             + gl.x*W_dist[128+k] + gl.y*W_dist[192+k] + b_dist[k];
            }
            for (int s = tid; s < 2048; s += 512) {
                int j = s >> 6, k = s & 63;
                float2 ac = reinterpret_cast<const float2*>(action)[p0 + j];
                float2 gl = reinterpret_cast<const float2*>(goal)[p0 + j];
                gDyn[j][k] = ac.x*W_dist[256+k] + ac.y*W_dist[320+k]
                           + gl.x*W_dist[384+k] + gl.y*W_dist[448+k];
            }
            __syncthreads();
            const int w  = tid >> 6;
            const int L  = tid & 63;
            const int q  = L >> 4;
            const int ln = L & 15;
            const bf16x8* Gf8 = reinterpret_cast<const bf16x8*>(ws + WS_GF);
            unsigned short* GATE = (unsigned short*)(ws + WS_GATE);
            #pragma unroll
            for (int e = 0; e < 2; ++e) {
                const int tile = w + e*8;          // 0..15 (row = i_local*32 + j)
                const int arow = tile*16 + ln;
                const int ai = arow >> 5, aj = arow & 31;
                bf16x8 afr[2];
                #pragma unroll
                for (int kt = 0; kt < 2; ++kt) {
                    bf16x8 a;
                    #pragma unroll
                    for (int jj = 0; jj < 8; ++jj) {
                        int k = kt*32 + q*8 + jj;
                        a[jj] = f2bf(fmaxf(gBase[ai][k] + gDyn[aj][k], 0.f));
                    }
                    afr[kt] = a;
                }
                for (int nt = 0; nt < 8; ++nt) {
                    float bg = b_gate[nt*16 + ln];
                    f32x4 a = { bg, bg, bg, bg };
                    a = __builtin_amdgcn_mfma_f32_16x16x32_bf16(afr[0], Gf8[(0*8+nt)*64 + L], a, 0, 0, 0);
                    a = __builtin_amdgcn_mfma_f32_16x16x32_bf16(afr[1], Gf8[(1*8+nt)*64 + L], a, 0, 0, 0);
                    #pragma unroll
                    for (int reg = 0; reg < 4; ++reg) {
                        int prow = tile*16 + q*4 + reg;
                        int il = prow >> 5, jr = prow & 31;
                        GATE[((size_t)(p0 + i0 + il)*32 + jr)*128 + nt*16 + ln] =
                            (unsigned short)f2bf(sigm(a[reg]));
                    }
                }
            }
        }
        return;
    }

    // ---- LSTM (R9/R10 structure: packed-weight preamble, dbuf X) ----
    __shared__ short Xl[2][16][KPAD];
    __shared__ float sEmb[192];

    const int ped0 = blockIdx.x * 8;
    const int w    = tid >> 6;
    const int lane = tid & 63;
    const int q    = lane >> 4;
    const int ln   = lane & 15;
    const int u    = w*16 + ln;

    if (tid < 192) sEmb[tid] = (tid < 128) ? W_emb[tid] : b_emb[tid - 128];

    const uint4* Lf4 = reinterpret_cast<const uint4*>(ws + WS_LF);
    bf16x8 bfr[4][6];
    #pragma unroll
    for (int idx = 0; idx < 4; ++idx) {
        #pragma unroll
        for (int kt = 0; kt < 6; ++kt) {
            uint4 r = Lf4[(size_t)(((w*4 + idx)*6 + kt)*64 + lane)];
            bfr[idx][kt] = *reinterpret_cast<bf16x8*>(&r);
        }
    }
    const float* bsvp = (const float*)(ws + WS_BSV);
    float bsv[4];
    #pragma unroll
    for (int idx = 0; idx < 4; ++idx) bsv[idx] = bsvp[idx*128 + u];

    float c_st[4];
    #pragma unroll
    for (int reg = 0; reg < 4; ++reg)
        c_st[reg] = c0[(size_t)(ped0 + ((q*4 + reg) & 7))*HDIM + u];

    #pragma unroll
    for (int reg = 0; reg < 4; ++reg)
        Xl[0][q*4 + reg][64 + u] = f2bf(h0[(size_t)(ped0 + ((q*4 + reg) & 7))*HDIM + u]);
    {
        const int pr = tid >> 5, d0 = (tid & 31)*2;    // pr 0..15 (mirror rows)
        const float2 ob = reinterpret_cast<const float2*>(obs)[(size_t)(ped0 + (pr & 7))];
        float x0 = fmaxf(ob.x*sEmb[d0]   + ob.y*sEmb[64+d0]   + sEmb[128+d0],   0.f);
        float x1 = fmaxf(ob.x*sEmb[d0+1] + ob.y*sEmb[64+d0+1] + sEmb[128+d0+1], 0.f);
        *reinterpret_cast<unsigned*>(&Xl[0][pr][d0]) = pk2(x0, x1);
    }
    __syncthreads();

    float hval[4];
    for (int t = 0; t < TOBS; ++t) {
        const int cur = t & 1, nxt = cur ^ 1;

        if (t < TOBS-1) {
            const int pr = tid >> 5, d0 = (tid & 31)*2;
            const float2 ob = reinterpret_cast<const float2*>(obs)[(size_t)((t+1)*N_PED + ped0 + (pr & 7))];
            float x0 = fmaxf(ob.x*sEmb[d0]   + ob.y*sEmb[64+d0]   + sEmb[128+d0],   0.f);
            float x1 = fmaxf(ob.x*sEmb[d0+1] + ob.y*sEmb[64+d0+1] + sEmb[128+d0+1], 0.f);
            *reinterpret_cast<unsigned*>(&Xl[nxt][pr][d0]) = pk2(x0, x1);
        }

        bf16x8 afr[6];
        #pragma unroll
        for (int kt = 0; kt < 6; ++kt)
            afr[kt] = *reinterpret_cast<const bf16x8*>(&Xl[cur][ln][kt*32 + q*8]);

        f32x4 acc[4];
        #pragma unroll
        for (int idx = 0; idx < 4; ++idx) {
            f32x4 a = { bsv[idx], bsv[idx], bsv[idx], bsv[idx] };
            #pragma unroll
            for (int kt = 0; kt < 6; ++kt)
                a = __builtin_amdgcn_mfma_f32_16x16x32_bf16(afr[kt], bfr[idx][kt], a, 0, 0, 0);
            acc[idx] = a;
        }
        #pragma unroll
        for (int reg = 0; reg < 4; ++reg) {
            float c = sigm(acc[1][reg])*c_st[reg] + sigm(acc[0][reg])*tanh_fast(acc[2][reg]);
            c_st[reg] = c;
            hval[reg] = sigm(acc[3][reg])*tanh_fast(c);
        }

        if (t < TOBS-1) {
            #pragma unroll
            for (int reg = 0; reg < 4; ++reg)
                Xl[nxt][q*4 + reg][64 + u] = f2bf(hval[reg]);
            __syncthreads();
        }
    }

    if (q < 2) {
        #pragma unroll
        for (int reg = 0; reg < 4; ++reg) {
            const size_t off = (size_t)(ped0 + q*4 + reg)*HDIM + u;
            AHb[off]  = (unsigned short)f2bf(hval[reg]);
            TAHb[off] = (unsigned short)f2bf(tanh_fast(hval[reg]));
        }
    }
}

// ---------------------------------------------------------------------------
// D3: GAT. 512 blocks x 256 thr, block = (group, 4 rows) in 2 halves.
// Phases (a)+(b) replaced by a load of the precomputed gate (x tanh_ah):
// fewer barriers, no sigmoids/dist-MLP, LDS ~39 KB.
// ---------------------------------------------------------------------------
__global__ __launch_bounds__(256) void gat_kernel(
    const unsigned short* __restrict__ AHb,
    const unsigned short* __restrict__ TAHb,
    const float* __restrict__ VW,
    const unsigned char* __restrict__ ws,     // Wf frags + GATE
    const float* __restrict__ ghs,
    const float* __restrict__ gat_bias,
    float* __restrict__ out)
{
    __shared__ unsigned short sGAb[80][136];
    __shared__ unsigned short sTAHb[32][136];
    __shared__ unsigned short sU[4][520];
    __shared__ float sAl[2][4][34];
    __shared__ float sPj[80][8];
    __shared__ float sgb[128];

    const int tid = threadIdx.x;
    const int g   = blockIdx.x >> 3;
    const int i0  = (blockIdx.x & 7) * 4;
    const int p0  = g * NPG;
    const int w   = tid >> 6;
    const int L   = tid & 63;
    const int q   = L >> 4;
    const int ln  = L & 15;

    const bf16x8* Wf8 = reinterpret_cast<const bf16x8*>(ws + WS_WF);
    const unsigned short* GATE = (const unsigned short*)(ws + WS_GATE);

    for (int s = tid; s < 512; s += 256) {
        int j = s >> 4, c = s & 15;
        *reinterpret_cast<uint4*>(&sTAHb[j][c*8]) =
            *reinterpret_cast<const uint4*>(&TAHb[(size_t)(p0 + j)*HDIM + c*8]);
    }
    if (tid < 128) sgb[tid] = gat_bias[tid];

    bf16x8 vf[4];
    #pragma unroll
    for (int kt = 0; kt < 4; ++kt) {
        bf16x8 bb;
        #pragma unroll
        for (int j = 0; j < 8; ++j) {
            int k = kt*32 + q*8 + j;
            float v = 0.f;
            if (ln < 4)      v = VW[ln*HDIM + k];
            else if (ln < 8) v = VW[512 + (ln-4)*HDIM + k];
            bb[j] = f2bf(v);
        }
        vf[kt] = bb;
    }
    __syncthreads();

    for (int half = 0; half < 2; ++half) {
        // (b') sGAb[rh*32+j][f] = gate[irow][j][f] * tanh_ah[j][f]
        #pragma unroll
        for (int rh = 0; rh < 2; ++rh) {
            const int irow = i0 + half*2 + rh;
            const uint4* gp = reinterpret_cast<const uint4*>(GATE + (size_t)(p0 + irow)*32*128);
            for (int s = tid; s < 512; s += 256) {
                int j = s >> 4, c = s & 15;
                uint4 gv = gp[s];
                uint4 tv = *reinterpret_cast<const uint4*>(&sTAHb[j][c*8]);
                unsigned r[4];
                #pragma unroll
                for (int e = 0; e < 4; ++e) {
                    unsigned gu = ((const unsigned*)&gv)[e];
                    unsigned tu = ((const unsigned*)&tv)[e];
                    float g0 = bf2f((unsigned short)(gu & 0xffffu)) * bf2f((unsigned short)(tu & 0xffffu));
                    float g1 = bf2f((unsigned short)(gu >> 16))     * bf2f((unsigned short)(tu >> 16));
                    r[e] = pk2(g0, g1);
                }
                *reinterpret_cast<uint4*>(&sGAb[rh*32 + j][c*8]) = uint4{r[0], r[1], r[2], r[3]};
            }
        }
        __syncthreads();

        // self rows := gh ; ah rows (64,65)
        {
            int rh = tid >> 7, f = tid & 127;
            int irow = i0 + half*2 + rh;
            sGAb[rh*32 + irow][f] = (unsigned short)f2bf(ghs[(size_t)(p0 + irow)*HDIM + f]);
            sGAb[64 + rh][f]      = AHb[(size_t)(p0 + irow)*HDIM + f];
        }
        __syncthreads();

        // (c) projections onto [V|W1]
        {
            int nmt = (w == 0) ? 2 : 1;
            for (int e = 0; e < nmt; ++e) {
                int mt = (e == 0) ? w : 4;
                bf16x8 afr;
                f32x4 a = { 0.f, 0.f, 0.f, 0.f };
                #pragma unroll
                for (int kt = 0; kt < 4; ++kt) {
                    afr = *reinterpret_cast<const bf16x8*>(&sGAb[mt*16 + ln][kt*32 + q*8]);
                    a = __builtin_amdgcn_mfma_f32_16x16x32_bf16(afr, vf[kt], a, 0, 0, 0);
                }
                if (ln < 8) {
                    #pragma unroll
                    for (int reg = 0; reg < 4; ++reg)
                        sPj[mt*16 + q*4 + reg][ln] = a[reg];
                }
            }
        }
        __syncthreads();

        // (d) softmax over 33 per (rh,h) — 4 partial sums for ILP
        if (tid < 8) {
            int rh = tid >> 2, h = tid & 3;
            float sa_ = sPj[64 + rh][4 + h];
            float x0  = sa_ + sPj[64 + rh][h];
            x0 = (x0 < 0.f) ? 0.2f*x0 : x0;
            sAl[rh][h][0] = 1.f;
            float s0 = 1.f, s1 = 0.f, s2 = 0.f, s3 = 0.f;
            #pragma unroll
            for (int k = 1; k <= 32; k += 4) {
                float xa = sa_ + sPj[rh*32 + k - 1][h];
                float xb = sa_ + sPj[rh*32 + k    ][h];
                float xc = sa_ + sPj[rh*32 + k + 1][h];
                float xd = sa_ + sPj[rh*32 + k + 2][h];
                xa = (xa < 0.f) ? 0.2f*xa : xa;  xb = (xb < 0.f) ? 0.2f*xb : xb;
                xc = (xc < 0.f) ? 0.2f*xc : xc;  xd = (xd < 0.f) ? 0.2f*xd : xd;
                float ea = __expf(xa - x0), eb = __expf(xb - x0);
                float ec = __expf(xc - x0), ed = __expf(xd - x0);
                sAl[rh][h][k]   = ea;  sAl[rh][h][k+1] = eb;
                sAl[rh][h][k+2] = ec;  sAl[rh][h][k+3] = ed;
                s0 += ea; s1 += eb; s2 += ec; s3 += ed;
            }
            float inv = __builtin_amdgcn_rcpf((s0 + s1) + (s2 + s3));
            for (int k = 0; k <= 32; ++k) sAl[rh][h][k] *= inv;
        }
        __syncthreads();

        // (e) u[h] = alpha-weighted sum
        {
            int rh = w & 1, ntb = (w >> 1) * 4;
            int r  = half*2 + rh;
            bf16x8 afr;
            #pragma unroll
            for (int jj = 0; jj < 8; ++jj)
                afr[jj] = f2bf(sAl[rh][ln & 3][1 + q*8 + jj]);
            for (int t = 0; t < 4; ++t) {
                int nt = ntb + t;
                bf16x8 bfr;
                #pragma unroll
                for (int jj = 0; jj < 8; ++jj)
                    bfr[jj] = (short)sGAb[rh*32 + q*8 + jj][nt*16 + ln];
                f32x4 a = { 0.f, 0.f, 0.f, 0.f };
                a = __builtin_amdgcn_mfma_f32_16x16x32_bf16(afr, bfr, a, 0, 0, 0);
                if (L < 16) {
                    #pragma unroll
                    for (int reg = 0; reg < 4; ++reg) {
                        float uv = a[reg] + sAl[rh][reg][0] * bf2f(sGAb[64 + rh][nt*16 + ln]);
                        sU[r][reg*HDIM + nt*16 + ln] = (unsigned short)f2bf(uv);
                    }
                }
            }
        }
        __syncthreads();
    }

    // (f) out = relu(0.25 * ucat @ wcat) + gat_bias
    {
        bf16x8 afr[16];
        #pragma unroll
        for (int kt = 0; kt < 16; ++kt)
            afr[kt] = *reinterpret_cast<const bf16x8*>(&sU[ln & 3][kt*32 + q*8]);
        for (int e = 0; e < 2; ++e) {
            int nt = w*2 + e;
            f32x4 a = { 0.f, 0.f, 0.f, 0.f };
            #pragma unroll
            for (int kt = 0; kt < 16; ++kt)
                a = __builtin_amdgcn_mfma_f32_16x16x32_bf16(afr[kt], Wf8[(kt*8+nt)*64 + L], a, 0, 0, 0);
            if (L < 16) {
                int o = nt*16 + ln;
                #pragma unroll
                for (int reg = 0; reg < 4; ++reg) {
                    float val = fmaxf(a[reg]*0.25f, 0.f) + sgb[o];
                    out[(size_t)(p0 + i0 + reg)*HDIM + o] = val;
                }
            }
        }
    }
}

// ---------------------------------------------------------------------------
extern "C" void kernel_launch(void* const* d_in, const int* in_sizes, int n_in,
                              void* d_out, int out_size, void* d_ws, size_t ws_size,
                              hipStream_t stream) {
    const float* obs      = (const float*)d_in[0];
    const float* ghs      = (const float*)d_in[1];
    const float* goal     = (const float*)d_in[2];
    const float* action   = (const float*)d_in[3];
    const float* h0       = (const float*)d_in[4];
    const float* c0       = (const float*)d_in[5];
    const float* W_emb    = (const float*)d_in[6];
    const float* b_emb    = (const float*)d_in[7];
    const float* W_ih     = (const float*)d_in[8];
    const float* W_hh     = (const float*)d_in[9];
    const float* b_ih     = (const float*)d_in[10];
    const float* b_hh     = (const float*)d_in[11];
    const float* W_dist   = (const float*)d_in[12];
    const float* b_dist   = (const float*)d_in[13];
    const float* W_gate   = (const float*)d_in[14];
    const float* b_gate   = (const float*)d_in[15];
    const float* gat_w    = (const float*)d_in[16];
    const float* gat_a    = (const float*)d_in[17];
    const float* gat_bias = (const float*)d_in[18];

    unsigned char* ws = (unsigned char*)d_ws;
    unsigned short* AHb  = (unsigned short*)(ws + WS_AHB);
    unsigned short* TAHb = (unsigned short*)(ws + WS_TAHB);
    float* VW            = (float*)(ws + WS_VW);
    float* out = (float*)d_out;

    hipLaunchKernelGGL(pack1_kernel, dim3(27), dim3(512), 0, stream,
                       W_ih, W_hh, b_ih, b_hh, W_gate, ws);
    hipLaunchKernelGGL(lstm_fused_kernel, dim3(544), dim3(512), 0, stream,
                       obs, h0, c0, W_emb, b_emb, gat_w, gat_a,
                       action, goal, W_dist, b_dist, b_gate, ws, AHb, TAHb);
    hipLaunchKernelGGL(gat_kernel, dim3(512), dim3(256), 0, stream,
                       AHb, TAHb, VW, ws, ghs, gat_bias, out);
}

// Round 12
// 127.958 us; speedup vs baseline: 1.0605x; 1.0605x over previous
//
#include <hip/hip_runtime.h>

// Problem constants (fixed by setup_inputs)
#define N_PED 2048
#define NGROUP 64
#define NPG 32        // peds per group
#define HDIM 128
#define DIN 64
#define DDIM 64
#define NHEAD 4
#define TOBS 8

typedef __attribute__((ext_vector_type(8))) short bf16x8;
typedef __attribute__((ext_vector_type(4))) float f32x4;

__device__ __forceinline__ float sigm(float x){
    return __builtin_amdgcn_rcpf(1.f + __expf(-x));
}
__device__ __forceinline__ float tanh_fast(float x){
    return 1.f - 2.f*__builtin_amdgcn_rcpf(__expf(2.f*x) + 1.f);
}
__device__ __forceinline__ short f2bf(float f){
    unsigned u = __float_as_uint(f);
    unsigned r = (u + 0x7fffu + ((u >> 16) & 1u)) >> 16;   // RNE
    return (short)r;
}
__device__ __forceinline__ float bf2f(unsigned short b){
    return __uint_as_float(((unsigned)b) << 16);
}
__device__ __forceinline__ unsigned pk2(float a, float b){
    return (unsigned)(unsigned short)f2bf(a) | ((unsigned)(unsigned short)f2bf(b) << 16);
}

// ws layout (bytes):
//   AHb  @ 0        : 2048*128 ushort (bf16)      524288
//   TAHb @ 524288   : 2048*128 ushort             524288
//   VW   @ 1048576  : 1024 f32 (V | W1)             4096
//   Gf   @ 1052672  : W_gate B-frags  16*64*16B    16384
//   Wf   @ 1069056  : gat_w  B-frags 128*64*16B   131072
//   Lf   @ 1200128  : LSTM W B-frags 192*64*16B   196608
//   BSV  @ 1396736  : b_ih+b_hh fused, 512 f32      2048
#define WS_AHB   0
#define WS_TAHB  524288
#define WS_VW    1048576
#define WS_GF    1052672
#define WS_WF    1069056
#define WS_LF    1200128
#define WS_BSV   1396736

// ---------------------------------------------------------------------------
// D1: pack ONLY what lstm needs (Lf B-frags + fused bias). 25 blocks — tiny.
// The gat-side prep (VW/Gf/Wf) is deferred into D2 to overlap with lstm.
// ---------------------------------------------------------------------------
__global__ __launch_bounds__(512) void pack_lstm_kernel(
    const float* __restrict__ W_ih,  const float* __restrict__ W_hh,
    const float* __restrict__ b_ih,  const float* __restrict__ b_hh,
    unsigned char* __restrict__ ws)
{
    const int tid = threadIdx.x;
    const int b   = blockIdx.x;
    if (b < 24) {
        // Lf pack: fid = (w*4+idx)*6+kt ; lane L = (q,ln) holds
        //   Wcat[k = kt*32+q*8+j][n = idx*128 + w*16 + ln], j=0..7
        const int id = b*512 + tid;             // 0..12287
        const int fid = id >> 6, L = id & 63;
        const int kt  = fid % 6;
        const int wi  = fid / 6;                // w*4 + idx
        const int w   = wi >> 2, idx = wi & 3;
        const int q = L >> 4, ln = L & 15;
        const int n = idx*128 + w*16 + ln;
        float v[8];
        if (kt < 2) {
            const float* src = W_ih + (size_t)n*DIN + kt*32 + q*8;
            #pragma unroll
            for (int j = 0; j < 8; ++j) v[j] = src[j];
        } else {
            const float* src = W_hh + (size_t)n*HDIM + (kt-2)*32 + q*8;
            #pragma unroll
            for (int j = 0; j < 8; ++j) v[j] = src[j];
        }
        reinterpret_cast<uint4*>(ws + WS_LF)[id] =
            uint4{ pk2(v[0],v[1]), pk2(v[2],v[3]), pk2(v[4],v[5]), pk2(v[6],v[7]) };
    } else {
        ((float*)(ws + WS_BSV))[tid] = b_ih[tid] + b_hh[tid];
    }
}

// ---------------------------------------------------------------------------
// D2: lstm (blocks 0..255) + gat-side prep/pack (blocks 256..289) fused.
// The prep/pack blocks are independent of lstm and hide behind it.
// ---------------------------------------------------------------------------
#define KPAD 216
__global__ __launch_bounds__(512) void lstm_fused_kernel(
    const float* __restrict__ obs, const float* __restrict__ h0,
    const float* __restrict__ c0,  const float* __restrict__ W_emb,
    const float* __restrict__ b_emb,
    const float* __restrict__ gat_w, const float* __restrict__ gat_a,
    const float* __restrict__ W_gate,
    unsigned char* __restrict__ ws,
    unsigned short* __restrict__ AHb, unsigned short* __restrict__ TAHb)
{
    const int tid = threadIdx.x;

    if (blockIdx.x >= 256) {
        const int vb = blockIdx.x - 256;
        if (vb < 16) {
            // ---- prep: V[h][f] = w[h][f]·a2, W1[h][f] = w[h][f]·a1 ----
            __shared__ float sa[2*HDIM];
            __shared__ float red[32][8][2];
            float* VW = (float*)(ws + WS_VW);
            if (tid < 256) sa[tid] = gat_a[tid];
            __syncthreads();
            const int rl = (tid & 255) >> 3, ch = tid & 7;
            const int row = vb*32 + rl;          // row = h*128 + f
            if (tid < 256) {
                const float* rp = gat_w + (size_t)row*HDIM + ch*16;
                float v = 0.f, w1 = 0.f;
                #pragma unroll
                for (int e = 0; e < 16; ++e) {
                    float wv = rp[e];
                    v  += wv * sa[HDIM + ch*16 + e];
                    w1 += wv * sa[ch*16 + e];
                }
                red[rl][ch][0] = v; red[rl][ch][1] = w1;
            }
            __syncthreads();
            if (tid < 256 && ch == 0) {
                float sv = 0.f, sw = 0.f;
                #pragma unroll
                for (int e = 0; e < 8; ++e) { sv += red[rl][e][0]; sw += red[rl][e][1]; }
                VW[row]       = sv;
                VW[512 + row] = sw;
            }
        } else {
            // ---- Gf/Wf pack ----
            const int id = (vb - 16)*512 + tid;
            if (id >= 9216) return;
            uint4* Gf4 = reinterpret_cast<uint4*>(ws + WS_GF);
            uint4* Wf4 = reinterpret_cast<uint4*>(ws + WS_WF);
            if (id < 1024) {
                const int fid = id >> 6, L = id & 63;
                const int kt = fid >> 3, nt = fid & 7;
                const int q = L >> 4, ln = L & 15;
                float v[8];
                #pragma unroll
                for (int j = 0; j < 8; ++j)
                    v[j] = W_gate[(size_t)(kt*32 + q*8 + j)*HDIM + nt*16 + ln];
                Gf4[id] = uint4{ pk2(v[0],v[1]), pk2(v[2],v[3]), pk2(v[4],v[5]), pk2(v[6],v[7]) };
            } else {
                const int id2 = id - 1024;
                const int fid = id2 >> 6, L = id2 & 63;
                const int kt = fid >> 3, nt = fid & 7;
                const int q = L >> 4, ln = L & 15;
                float v[8];
                #pragma unroll
                for (int j = 0; j < 8; ++j) {
                    int F = kt*32 + q*8 + j;               // F = h*128 + f
                    v[j] = gat_w[(size_t)(F >> 7)*16384 + (size_t)(F & 127)*HDIM + nt*16 + ln];
                }
                Wf4[id2] = uint4{ pk2(v[0],v[1]), pk2(v[2],v[3]), pk2(v[4],v[5]), pk2(v[6],v[7]) };
            }
        }
        return;
    }

    // ---- LSTM (R9 structure: packed-weight preamble, double-buffered X) ----
    __shared__ short Xl[2][16][KPAD];
    __shared__ float sEmb[192];

    const int ped0 = blockIdx.x * 8;
    const int w    = tid >> 6;
    const int lane = tid & 63;
    const int q    = lane >> 4;
    const int ln   = lane & 15;
    const int u    = w*16 + ln;

    if (tid < 192) sEmb[tid] = (tid < 128) ? W_emb[tid] : b_emb[tid - 128];

    const uint4* Lf4 = reinterpret_cast<const uint4*>(ws + WS_LF);
    bf16x8 bfr[4][6];
    #pragma unroll
    for (int idx = 0; idx < 4; ++idx) {
        #pragma unroll
        for (int kt = 0; kt < 6; ++kt) {
            uint4 r = Lf4[(size_t)(((w*4 + idx)*6 + kt)*64 + lane)];
            bfr[idx][kt] = *reinterpret_cast<bf16x8*>(&r);
        }
    }
    const float* bsvp = (const float*)(ws + WS_BSV);
    float bsv[4];
    #pragma unroll
    for (int idx = 0; idx < 4; ++idx) bsv[idx] = bsvp[idx*128 + u];

    float c_st[4];
    #pragma unroll
    for (int reg = 0; reg < 4; ++reg)
        c_st[reg] = c0[(size_t)(ped0 + ((q*4 + reg) & 7))*HDIM + u];

    // stage h0 (mirrored rows) + x_0 into buffer 0
    #pragma unroll
    for (int reg = 0; reg < 4; ++reg)
        Xl[0][q*4 + reg][64 + u] = f2bf(h0[(size_t)(ped0 + ((q*4 + reg) & 7))*HDIM + u]);
    {
        const int pr = tid >> 5, d0 = (tid & 31)*2;    // pr 0..15 (mirror rows)
        const float2 ob = reinterpret_cast<const float2*>(obs)[(size_t)(ped0 + (pr & 7))];
        float x0 = fmaxf(ob.x*sEmb[d0]   + ob.y*sEmb[64+d0]   + sEmb[128+d0],   0.f);
        float x1 = fmaxf(ob.x*sEmb[d0+1] + ob.y*sEmb[64+d0+1] + sEmb[128+d0+1], 0.f);
        *reinterpret_cast<unsigned*>(&Xl[0][pr][d0]) = pk2(x0, x1);
    }
    __syncthreads();

    float hval[4];
    for (int t = 0; t < TOBS; ++t) {
        const int cur = t & 1, nxt = cur ^ 1;

        if (t < TOBS-1) {
            const int pr = tid >> 5, d0 = (tid & 31)*2;
            const float2 ob = reinterpret_cast<const float2*>(obs)[(size_t)((t+1)*N_PED + ped0 + (pr & 7))];
            float x0 = fmaxf(ob.x*sEmb[d0]   + ob.y*sEmb[64+d0]   + sEmb[128+d0],   0.f);
            float x1 = fmaxf(ob.x*sEmb[d0+1] + ob.y*sEmb[64+d0+1] + sEmb[128+d0+1], 0.f);
            *reinterpret_cast<unsigned*>(&Xl[nxt][pr][d0]) = pk2(x0, x1);
        }

        bf16x8 afr[6];
        #pragma unroll
        for (int kt = 0; kt < 6; ++kt)
            afr[kt] = *reinterpret_cast<const bf16x8*>(&Xl[cur][ln][kt*32 + q*8]);

        f32x4 acc[4];
        #pragma unroll
        for (int idx = 0; idx < 4; ++idx) {
            f32x4 a = { bsv[idx], bsv[idx], bsv[idx], bsv[idx] };
            #pragma unroll
            for (int kt = 0; kt < 6; ++kt)
                a = __builtin_amdgcn_mfma_f32_16x16x32_bf16(afr[kt], bfr[idx][kt], a, 0, 0, 0);
            acc[idx] = a;
        }
        #pragma unroll
        for (int reg = 0; reg < 4; ++reg) {
            float c = sigm(acc[1][reg])*c_st[reg] + sigm(acc[0][reg])*tanh_fast(acc[2][reg]);
            c_st[reg] = c;
            hval[reg] = sigm(acc[3][reg])*tanh_fast(c);
        }

        if (t < TOBS-1) {
            #pragma unroll
            for (int reg = 0; reg < 4; ++reg)
                Xl[nxt][q*4 + reg][64 + u] = f2bf(hval[reg]);
            __syncthreads();
        }
    }

    if (q < 2) {
        #pragma unroll
        for (int reg = 0; reg < 4; ++reg) {
            const size_t off = (size_t)(ped0 + q*4 + reg)*HDIM + u;
            AHb[off]  = (unsigned short)f2bf(hval[reg]);
            TAHb[off] = (unsigned short)f2bf(tanh_fast(hval[reg]));
        }
    }
}

// ---------------------------------------------------------------------------
// D3: GAT, MFMA edition (R9/R10 measured-best shape, unchanged):
// 512 blocks x 256 thr, block = (group, 4 rows) in 2 serial halves.
// ---------------------------------------------------------------------------
__global__ __launch_bounds__(256) void gat_kernel(
    const unsigned short* __restrict__ AHb,
    const unsigned short* __restrict__ TAHb,
    const float* __restrict__ VW,
    const unsigned char* __restrict__ ws,     // Gf/Wf frags
    const float* __restrict__ ghs,
    const float* __restrict__ goal,
    const float* __restrict__ action,
    const float* __restrict__ W_dist,
    const float* __restrict__ b_dist,
    const float* __restrict__ b_gate,
    const float* __restrict__ gat_bias,
    float* __restrict__ out)
{
    __shared__ unsigned short sGAb[80][136];
    __shared__ unsigned short sTAHb[32][136];
    __shared__ unsigned short st1b[64][72];
    __shared__ unsigned short sU[4][520];
    __shared__ float sAl[2][4][34];
    __shared__ float sPj[80][8];
    __shared__ float sWd[8][64];
    __shared__ float sbd[64];
    __shared__ float sbg[128];
    __shared__ float sgb[128];
    __shared__ float sAC[32][2], sGL[32][2];

    const int tid = threadIdx.x;
    const int g   = blockIdx.x >> 3;
    const int i0  = (blockIdx.x & 7) * 4;
    const int p0  = g * NPG;
    const int w   = tid >> 6;
    const int L   = tid & 63;
    const int q   = L >> 4;
    const int ln  = L & 15;

    const bf16x8* Gf8 = reinterpret_cast<const bf16x8*>(ws + WS_GF);
    const bf16x8* Wf8 = reinterpret_cast<const bf16x8*>(ws + WS_WF);

    for (int s = tid; s < 512; s += 256) {
        int j = s >> 4, c = s & 15;
        *reinterpret_cast<uint4*>(&sTAHb[j][c*8]) =
            *reinterpret_cast<const uint4*>(&TAHb[(size_t)(p0 + j)*HDIM + c*8]);
    }
    if (tid < 128) {
        sbg[tid] = b_gate[tid];
        sgb[tid] = gat_bias[tid];
    } else if (tid < 192) {
        sbd[tid-128] = b_dist[tid-128];
    } else {
        int j = tid - 192;
        int pd = j & 31;
        if (j < 32) { const float2 a = reinterpret_cast<const float2*>(action)[p0+pd];
                      sAC[pd][0]=a.x; sAC[pd][1]=a.y; }
        else        { const float2 gl = reinterpret_cast<const float2*>(goal)[p0+pd];
                      sGL[pd][0]=gl.x; sGL[pd][1]=gl.y; }
    }
    if (tid < 256) {
        int rr = tid >> 6, k = tid & 63;
        sWd[rr][k]   = W_dist[rr*64 + k];
        sWd[rr+4][k] = W_dist[(rr+4)*64 + k];
    }

    bf16x8 vf[4];
    #pragma unroll
    for (int kt = 0; kt < 4; ++kt) {
        bf16x8 bb;
        #pragma unroll
        for (int j = 0; j < 8; ++j) {
            int k = kt*32 + q*8 + j;
            float v = 0.f;
            if (ln < 4)      v = VW[ln*HDIM + k];
            else if (ln < 8) v = VW[512 + (ln-4)*HDIM + k];
            bb[j] = f2bf(v);
        }
        vf[kt] = bb;
    }
    __syncthreads();

    for (int half = 0; half < 2; ++half) {
        // (a) t1 = relu(dist @ W_dist + b_dist)
        {
            const int k = tid & 63, mg = tid >> 6;
            float base[2];
            #pragma unroll
            for (int rh = 0; rh < 2; ++rh) {
                int i = i0 + half*2 + rh;
                base[rh] = sAC[i][0]*sWd[0][k] + sAC[i][1]*sWd[1][k]
                         + sGL[i][0]*sWd[2][k] + sGL[i][1]*sWd[3][k] + sbd[k];
            }
            #pragma unroll
            for (int mm = 0; mm < 16; ++mm) {
                int m = mg*16 + mm, j = m & 31;
                float v = base[m>>5] + sAC[j][0]*sWd[4][k] + sAC[j][1]*sWd[5][k]
                                     + sGL[j][0]*sWd[6][k] + sGL[j][1]*sWd[7][k];
                st1b[m][k] = (unsigned short)f2bf(fmaxf(v, 0.f));
            }
        }
        __syncthreads();

        // (b) gate MLP layer 2 via MFMA + sigmoid*tanh_ah
        {
            bf16x8 afr[2];
            #pragma unroll
            for (int kt = 0; kt < 2; ++kt)
                afr[kt] = *reinterpret_cast<const bf16x8*>(&st1b[w*16 + ln][kt*32 + q*8]);
            for (int nt = 0; nt < 8; ++nt) {
                float bg = sbg[nt*16 + ln];
                f32x4 a = { bg, bg, bg, bg };
                a = __builtin_amdgcn_mfma_f32_16x16x32_bf16(afr[0], Gf8[(0*8+nt)*64 + L], a, 0, 0, 0);
                a = __builtin_amdgcn_mfma_f32_16x16x32_bf16(afr[1], Gf8[(1*8+nt)*64 + L], a, 0, 0, 0);
                #pragma unroll
                for (int reg = 0; reg < 4; ++reg) {
                    int mrow = w*16 + q*4 + reg;
                    int n = nt*16 + ln;
                    float ga = sigm(a[reg]) * bf2f(sTAHb[mrow & 31][n]);
                    sGAb[mrow][n] = (unsigned short)f2bf(ga);
                }
            }
        }
        __syncthreads();

        // self rows := gh ; ah rows (64,65)
        {
            int rh = tid >> 7, f = tid & 127;
            int irow = i0 + half*2 + rh;
            sGAb[rh*32 + irow][f] = (unsigned short)f2bf(ghs[(size_t)(p0 + irow)*HDIM + f]);
            sGAb[64 + rh][f]      = AHb[(size_t)(p0 + irow)*HDIM + f];
        }
        __syncthreads();

        // (c) projections onto [V|W1]
        {
            int nmt = (w == 0) ? 2 : 1;
            for (int e = 0; e < nmt; ++e) {
                int mt = (e == 0) ? w : 4;
                bf16x8 afr;
                f32x4 a = { 0.f, 0.f, 0.f, 0.f };
                #pragma unroll
                for (int kt = 0; kt < 4; ++kt) {
                    afr = *reinterpret_cast<const bf16x8*>(&sGAb[mt*16 + ln][kt*32 + q*8]);
                    a = __builtin_amdgcn_mfma_f32_16x16x32_bf16(afr, vf[kt], a, 0, 0, 0);
                }
                if (ln < 8) {
                    #pragma unroll
                    for (int reg = 0; reg < 4; ++reg)
                        sPj[mt*16 + q*4 + reg][ln] = a[reg];
                }
            }
        }
        __syncthreads();

        // (d) softmax over 33 per (rh,h) — 4 partial sums for ILP
        if (tid < 8) {
            int rh = tid >> 2, h = tid & 3;
            float sa_ = sPj[64 + rh][4 + h];
            float x0  = sa_ + sPj[64 + rh][h];
            x0 = (x0 < 0.f) ? 0.2f*x0 : x0;
            sAl[rh][h][0] = 1.f;
            float s0 = 1.f, s1 = 0.f, s2 = 0.f, s3 = 0.f;
            #pragma unroll
            for (int k = 1; k <= 32; k += 4) {
                float xa = sa_ + sPj[rh*32 + k - 1][h];
                float xb = sa_ + sPj[rh*32 + k    ][h];
                float xc = sa_ + sPj[rh*32 + k + 1][h];
                float xd = sa_ + sPj[rh*32 + k + 2][h];
                xa = (xa < 0.f) ? 0.2f*xa : xa;  xb = (xb < 0.f) ? 0.2f*xb : xb;
                xc = (xc < 0.f) ? 0.2f*xc : xc;  xd = (xd < 0.f) ? 0.2f*xd : xd;
                float ea = __expf(xa - x0), eb = __expf(xb - x0);
                float ec = __expf(xc - x0), ed = __expf(xd - x0);
                sAl[rh][h][k]   = ea;  sAl[rh][h][k+1] = eb;
                sAl[rh][h][k+2] = ec;  sAl[rh][h][k+3] = ed;
                s0 += ea; s1 += eb; s2 += ec; s3 += ed;
            }
            float inv = __builtin_amdgcn_rcpf((s0 + s1) + (s2 + s3));
            for (int k = 0; k <= 32; ++k) sAl[rh][h][k] *= inv;
        }
        __syncthreads();

        // (e) u[h] = alpha-weighted sum
        {
            int rh = w & 1, ntb = (w >> 1) * 4;
            int r  = half*2 + rh;
            bf16x8 afr;
            #pragma unroll
            for (int jj = 0; jj < 8; ++jj)
                afr[jj] = f2bf(sAl[rh][ln & 3][1 + q*8 + jj]);
            for (int t = 0; t < 4; ++t) {
                int nt = ntb + t;
                bf16x8 bfr;
                #pragma unroll
                for (int jj = 0; jj < 8; ++jj)
                    bfr[jj] = (short)sGAb[rh*32 + q*8 + jj][nt*16 + ln];
                f32x4 a = { 0.f, 0.f, 0.f, 0.f };
                a = __builtin_amdgcn_mfma_f32_16x16x32_bf16(afr, bfr, a, 0, 0, 0);
                if (L < 16) {
                    #pragma unroll
                    for (int reg = 0; reg < 4; ++reg) {
                        float uv = a[reg] + sAl[rh][reg][0] * bf2f(sGAb[64 + rh][nt*16 + ln]);
                        sU[r][reg*HDIM + nt*16 + ln] = (unsigned short)f2bf(uv);
                    }
                }
            }
        }
        __syncthreads();
    }

    // (f) out = relu(0.25 * ucat @ wcat) + gat_bias
    {
        bf16x8 afr[16];
        #pragma unroll
        for (int kt = 0; kt < 16; ++kt)
            afr[kt] = *reinterpret_cast<const bf16x8*>(&sU[ln & 3][kt*32 + q*8]);
        for (int e = 0; e < 2; ++e) {
            int nt = w*2 + e;
            f32x4 a = { 0.f, 0.f, 0.f, 0.f };
            #pragma unroll
            for (int kt = 0; kt < 16; ++kt)
                a = __builtin_amdgcn_mfma_f32_16x16x32_bf16(afr[kt], Wf8[(kt*8+nt)*64 + L], a, 0, 0, 0);
            if (L < 16) {
                int o = nt*16 + ln;
                #pragma unroll
                for (int reg = 0; reg < 4; ++reg) {
                    float val = fmaxf(a[reg]*0.25f, 0.f) + sgb[o];
                    out[(size_t)(p0 + i0 + reg)*HDIM + o] = val;
                }
            }
        }
    }
}

// ---------------------------------------------------------------------------
extern "C" void kernel_launch(void* const* d_in, const int* in_sizes, int n_in,
                              void* d_out, int out_size, void* d_ws, size_t ws_size,
                              hipStream_t stream) {
    const float* obs      = (const float*)d_in[0];
    const float* ghs      = (const float*)d_in[1];
    const float* goal     = (const float*)d_in[2];
    const float* action   = (const float*)d_in[3];
    const float* h0       = (const float*)d_in[4];
    const float* c0       = (const float*)d_in[5];
    const float* W_emb    = (const float*)d_in[6];
    const float* b_emb    = (const float*)d_in[7];
    const float* W_ih     = (const float*)d_in[8];
    const float* W_hh     = (const float*)d_in[9];
    const float* b_ih     = (const float*)d_in[10];
    const float* b_hh     = (const float*)d_in[11];
    const float* W_dist   = (const float*)d_in[12];
    const float* b_dist   = (const float*)d_in[13];
    const float* W_gate   = (const float*)d_in[14];
    const float* b_gate   = (const float*)d_in[15];
    const float* gat_w    = (const float*)d_in[16];
    const float* gat_a    = (const float*)d_in[17];
    const float* gat_bias = (const float*)d_in[18];

    unsigned char* ws = (unsigned char*)d_ws;
    unsigned short* AHb  = (unsigned short*)(ws + WS_AHB);
    unsigned short* TAHb = (unsigned short*)(ws + WS_TAHB);
    float* VW            = (float*)(ws + WS_VW);
    float* out = (float*)d_out;

    hipLaunchKernelGGL(pack_lstm_kernel, dim3(25), dim3(512), 0, stream,
                       W_ih, W_hh, b_ih, b_hh, ws);
    hipLaunchKernelGGL(lstm_fused_kernel, dim3(290), dim3(512), 0, stream,
                       obs, h0, c0, W_emb, b_emb, gat_w, gat_a, W_gate, ws, AHb, TAHb);
    hipLaunchKernelGGL(gat_kernel, dim3(512), dim3(256), 0, stream,
                       AHb, TAHb, VW, ws, ghs, goal, action,
                       W_dist, b_dist, b_gate, gat_bias, out);
}